// Round 1
// baseline (255.914 us; speedup 1.0000x reference)
//
#include <hip/hip_runtime.h>
#include <hip/hip_bf16.h>
#include <stdint.h>

#define N 8192
#define E 256
#define NUM_CLASSES 100
#define MARGIN 0.1f
#define EPS 1e-4f

#define BM 128
#define BN 128
#define BK 32
#define E_BYTES (E * 2)  // bf16 row = 512 B

typedef __attribute__((ext_vector_type(8))) short short8;   // 8 bf16 (4 VGPRs)
typedef __attribute__((ext_vector_type(4))) float floatx4;  // MFMA C/D

typedef const __attribute__((address_space(1))) void* gptr_t;
typedef __attribute__((address_space(3))) void* sptr_t;

// --- Kernel 1: bf16 cast + row squared-norms + class histogram ---------------
__global__ __launch_bounds__(256) void prep_kernel(
    const float* __restrict__ emb, const int* __restrict__ labels,
    __hip_bfloat16* __restrict__ Ebf, float* __restrict__ sq, int* __restrict__ cnt)
{
  const int row = blockIdx.x;
  const int t = threadIdx.x;
  float x = emb[(size_t)row * E + t];
  Ebf[(size_t)row * E + t] = __float2bfloat16(x);
  float s = x * x;
  #pragma unroll
  for (int off = 32; off > 0; off >>= 1) s += __shfl_down(s, off, 64);
  __shared__ float ws4[4];
  if ((t & 63) == 0) ws4[t >> 6] = s;
  __syncthreads();
  if (t == 0) {
    sq[row] = ws4[0] + ws4[1] + ws4[2] + ws4[3];
    atomicAdd(&cnt[labels[row]], 1);
  }
}

// --- Kernel 2: 128x128-tile bf16 MFMA Gram + fused triplet epilogue ----------
// Block = 256 threads = 4 waves (2x2), each wave computes 64x64 via 4x4 grid
// of 16x16x32 MFMAs. K-loop over E=256 in BK=32 steps, global_load_lds x16B
// staging (m97 pattern). Epilogue: d=sqrt(max(sq_a+sq_j-2*dot,EPS)), row-sums
// of pos*d and neg/(d+margin) via 16-lane xor-shuffle, atomicAdd per row.
__global__ __launch_bounds__(256) void gram_kernel(
    const __hip_bfloat16* __restrict__ Ebf, const float* __restrict__ sq,
    const int* __restrict__ labels, float* __restrict__ numv, float* __restrict__ denv)
{
  __shared__ alignas(16) __hip_bfloat16 As[BM * BK];  // 8 KB, [128][32] row-major
  __shared__ alignas(16) __hip_bfloat16 Bs[BN * BK];  // 8 KB

  const int tid = threadIdx.x;
  const int lane = tid & 63;
  const int wave = tid >> 6;
  const int waveM = wave >> 1;
  const int waveN = wave & 1;
  const int quad = lane >> 4;
  const int l16 = lane & 15;

  const int rowBase = blockIdx.y * BM;
  const int colBase = blockIdx.x * BN;

  floatx4 acc[4][4];
  #pragma unroll
  for (int i = 0; i < 4; ++i)
    #pragma unroll
    for (int j = 0; j < 4; ++j)
      acc[i][j] = (floatx4){0.f, 0.f, 0.f, 0.f};

  const char* gbase = (const char*)Ebf;

  for (int k0 = 0; k0 < E; k0 += BK) {
    // Stage A and B tiles: 8 KB each = 2 iters x 256 threads x 16 B.
    // LDS layout is exactly linear in lane order (global_load_lds requirement:
    // wave-uniform base + lane*16).
    #pragma unroll
    for (int it = 0; it < 2; ++it) {
      int p = (it * 256 + tid) * 16;  // byte offset in 8 KB tile
      int r = p >> 6;                 // 64 B per k-row
      int cb = p & 63;
      const char* gA = gbase + (size_t)(rowBase + r) * E_BYTES + k0 * 2 + cb;
      const char* gB = gbase + (size_t)(colBase + r) * E_BYTES + k0 * 2 + cb;
      __builtin_amdgcn_global_load_lds((gptr_t)gA, (sptr_t)((char*)As + p), 16, 0, 0);
      __builtin_amdgcn_global_load_lds((gptr_t)gB, (sptr_t)((char*)Bs + p), 16, 0, 0);
    }
    __syncthreads();  // compiler emits vmcnt(0) drain before s_barrier

    // A-frag: A[m=l16][k=quad*8+j]; B-frag: B[n=l16][k=quad*8+j] — for C=X*X^T
    // both operands load rows of X identically.
    short8 afrag[4], bfrag[4];
    #pragma unroll
    for (int mi = 0; mi < 4; ++mi)
      afrag[mi] = *(const short8*)(As + (waveM * 64 + mi * 16 + l16) * BK + quad * 8);
    #pragma unroll
    for (int ni = 0; ni < 4; ++ni)
      bfrag[ni] = *(const short8*)(Bs + (waveN * 64 + ni * 16 + l16) * BK + quad * 8);

    #pragma unroll
    for (int mi = 0; mi < 4; ++mi)
      #pragma unroll
      for (int ni = 0; ni < 4; ++ni)
        acc[mi][ni] = __builtin_amdgcn_mfma_f32_16x16x32_bf16(
            afrag[mi], bfrag[ni], acc[mi][ni], 0, 0, 0);

    __syncthreads();  // protect LDS before next stage overwrites
  }

  // Epilogue. C/D layout: col = lane&15, row = quad*4 + reg (verified m89).
  float sqc[4];
  int lc[4];
  #pragma unroll
  for (int ni = 0; ni < 4; ++ni) {
    int col = colBase + waveN * 64 + ni * 16 + l16;
    sqc[ni] = sq[col];
    lc[ni] = labels[col];
  }

  #pragma unroll
  for (int mi = 0; mi < 4; ++mi) {
    #pragma unroll
    for (int r = 0; r < 4; ++r) {
      const int row = rowBase + waveM * 64 + mi * 16 + quad * 4 + r;
      const float sqr = sq[row];
      const int lr = labels[row];
      float np = 0.f, dp = 0.f;
      #pragma unroll
      for (int ni = 0; ni < 4; ++ni) {
        float d2 = sqr + sqc[ni] - 2.f * acc[mi][ni][r];
        d2 = fmaxf(d2, EPS);  // max(res,0) then max(.,EPS) == max(res,EPS)
        float d = __builtin_amdgcn_sqrtf(d2);
        bool same = (lr == lc[ni]);
        np += same ? d : 0.f;
        dp += same ? 0.f : __builtin_amdgcn_rcpf(d + MARGIN);
      }
      // reduce across the 16 lanes sharing this output row
      #pragma unroll
      for (int off = 1; off < 16; off <<= 1) {
        np += __shfl_xor(np, off, 64);
        dp += __shfl_xor(dp, off, 64);
      }
      if (l16 == 0) {
        atomicAdd(&numv[row], np);
        atomicAdd(&denv[row], dp);
      }
    }
  }
}

// --- Kernel 3: loss = sum_a num[a]*den[a] / sum_a c*(N-c), fp64 accum --------
__global__ __launch_bounds__(256) void finalize_kernel(
    const float* __restrict__ numv, const float* __restrict__ denv,
    const int* __restrict__ labels, const int* __restrict__ cnt,
    float* __restrict__ out)
{
  const int t = threadIdx.x;
  double s = 0.0, ms = 0.0;
  for (int a = t; a < N; a += 256) {
    s += (double)numv[a] * (double)denv[a];
    int pc = cnt[labels[a]];
    ms += (double)pc * (double)(N - pc);
  }
  #pragma unroll
  for (int off = 32; off > 0; off >>= 1) {
    s += __shfl_down(s, off, 64);
    ms += __shfl_down(ms, off, 64);
  }
  __shared__ double sh[8];
  if ((t & 63) == 0) {
    sh[t >> 6] = s;
    sh[4 + (t >> 6)] = ms;
  }
  __syncthreads();
  if (t == 0) {
    double S = sh[0] + sh[1] + sh[2] + sh[3];
    double M = sh[4] + sh[5] + sh[6] + sh[7];
    out[0] = (float)(S / M);
  }
}

extern "C" void kernel_launch(void* const* d_in, const int* in_sizes, int n_in,
                              void* d_out, int out_size, void* d_ws, size_t ws_size,
                              hipStream_t stream) {
  const float* emb = (const float*)d_in[0];
  const int* labels = (const int*)d_in[1];
  float* out = (float*)d_out;

  // Workspace layout (~4.3 MB): Ebf[N*E bf16] | sq[N f32] | num[N] | den[N] | cnt[100]
  char* w = (char*)d_ws;
  __hip_bfloat16* Ebf = (__hip_bfloat16*)w;
  float* sq = (float*)(w + (size_t)N * E * 2);
  float* numv = sq + N;
  float* denv = numv + N;
  int* cnt = (int*)(denv + N);

  // zero num/den/cnt (ws is poisoned 0xAA before every call)
  hipMemsetAsync(numv, 0, (size_t)(2 * N) * sizeof(float) + NUM_CLASSES * sizeof(int),
                 stream);

  prep_kernel<<<N, 256, 0, stream>>>(emb, labels, Ebf, sq, cnt);
  gram_kernel<<<dim3(N / BN, N / BM), 256, 0, stream>>>(Ebf, sq, labels, numv, denv);
  finalize_kernel<<<1, 256, 0, stream>>>(numv, denv, labels, cnt, out);
}

// Round 2
// 197.358 us; speedup vs baseline: 1.2967x; 1.2967x over previous
//
#include <hip/hip_runtime.h>
#include <hip/hip_bf16.h>
#include <stdint.h>

#define N 8192
#define E 256
#define NUM_CLASSES 100
#define MARGIN 0.1f
#define EPS 1e-4f

#define BM 128
#define BN 128
#define BK 64
#define E_BYTES (E * 2)  // bf16 row = 512 B

typedef __attribute__((ext_vector_type(8))) short short8;   // 8 bf16 (4 VGPRs)
typedef __attribute__((ext_vector_type(4))) float floatx4;  // MFMA C/D

typedef const __attribute__((address_space(1))) void* gptr_t;
typedef __attribute__((address_space(3))) void* sptr_t;

// --- Kernel 1: bf16 cast + row squared-norms + class histogram ---------------
// 512 blocks x 256 threads; each wave handles 4 rows, float4 per lane.
__global__ __launch_bounds__(256) void prep_kernel(
    const float* __restrict__ emb, const int* __restrict__ labels,
    __hip_bfloat16* __restrict__ Ebf, float* __restrict__ sq, int* __restrict__ cnt)
{
  const int lane = threadIdx.x & 63;
  const int wave = threadIdx.x >> 6;
  #pragma unroll
  for (int i = 0; i < 4; ++i) {
    const int row = blockIdx.x * 16 + i * 4 + wave;
    const float4 x = *(const float4*)(emb + (size_t)row * E + lane * 4);
    union { __hip_bfloat16 h[4]; ushort4 u; } pk;
    pk.h[0] = __float2bfloat16(x.x);
    pk.h[1] = __float2bfloat16(x.y);
    pk.h[2] = __float2bfloat16(x.z);
    pk.h[3] = __float2bfloat16(x.w);
    *(ushort4*)((unsigned short*)Ebf + (size_t)row * E + lane * 4) = pk.u;
    float s = x.x * x.x + x.y * x.y + x.z * x.z + x.w * x.w;
    #pragma unroll
    for (int off = 32; off > 0; off >>= 1) s += __shfl_down(s, off, 64);
    if (lane == 0) {
      sq[row] = s;
      atomicAdd(&cnt[labels[row]], 1);
    }
  }
}

// --- Kernel 2: symmetric 128x128-tile bf16 MFMA Gram + fused epilogue --------
// Only upper-triangle tiles (bx >= by). Off-diagonal tiles accumulate BOTH
// row-sums and (by symmetry) col-sums. LDS chunk layout is XOR-swizzled:
// 16B-chunk c of a tile holds (row r = c>>3, kchunk (c&7)^(r&7)) so that the
// short8 fragment reads (row stride 128 B) spread across all 8 bank-quads
// (2-way aliasing = free). global_load_lds dest stays linear (HW constraint).
__global__ __launch_bounds__(256) void gram_kernel(
    const __hip_bfloat16* __restrict__ Ebf, const float* __restrict__ sq,
    const int* __restrict__ labels, float* __restrict__ numv, float* __restrict__ denv)
{
  const int bx = blockIdx.x, by = blockIdx.y;
  if (bx < by) return;  // lower triangle: done by symmetry
  const bool diag = (bx == by);

  __shared__ alignas(16) __hip_bfloat16 As[BM * BK];  // 16 KB
  __shared__ alignas(16) __hip_bfloat16 Bs[BN * BK];  // 16 KB

  const int tid = threadIdx.x;
  const int lane = tid & 63;
  const int wave = tid >> 6;
  const int waveM = wave >> 1;
  const int waveN = wave & 1;
  const int quad = lane >> 4;
  const int l16 = lane & 15;

  const int rowBase = by * BM;
  const int colBase = bx * BN;

  floatx4 acc[4][4];
  #pragma unroll
  for (int i = 0; i < 4; ++i)
    #pragma unroll
    for (int j = 0; j < 4; ++j)
      acc[i][j] = (floatx4){0.f, 0.f, 0.f, 0.f};

  const char* gbase = (const char*)Ebf;

  for (int k0 = 0; k0 < E; k0 += BK) {
    // Stage 16 KB per tile = 4 rounds x 256 threads x 16 B, swizzled source.
    #pragma unroll
    for (int it = 0; it < 4; ++it) {
      const int c = it * 256 + tid;       // chunk index 0..1023
      const int r = c >> 3;               // tile row (128-B k-rows, 8 chunks)
      const int kq = (c & 7) ^ (r & 7);   // swizzled k-chunk
      const int srcoff = k0 * 2 + kq * 16;
      const int dstoff = c * 16;
      const char* gA = gbase + (size_t)(rowBase + r) * E_BYTES + srcoff;
      __builtin_amdgcn_global_load_lds((gptr_t)gA, (sptr_t)((char*)As + dstoff), 16, 0, 0);
      if (!diag) {
        const char* gB = gbase + (size_t)(colBase + r) * E_BYTES + srcoff;
        __builtin_amdgcn_global_load_lds((gptr_t)gB, (sptr_t)((char*)Bs + dstoff), 16, 0, 0);
      }
    }
    __syncthreads();

    const __hip_bfloat16* Bsrc = diag ? As : Bs;
    #pragma unroll
    for (int ks = 0; ks < 2; ++ks) {  // two K=32 MFMA steps per BK=64 stage
      const int q = ks * 4 + quad;
      short8 af[4], bf[4];
      #pragma unroll
      for (int mi = 0; mi < 4; ++mi) {
        const int r = waveM * 64 + mi * 16 + l16;
        af[mi] = *(const short8*)((const char*)As + (r * 8 + (q ^ (r & 7))) * 16);
      }
      #pragma unroll
      for (int ni = 0; ni < 4; ++ni) {
        const int r = waveN * 64 + ni * 16 + l16;
        bf[ni] = *(const short8*)((const char*)Bsrc + (r * 8 + (q ^ (r & 7))) * 16);
      }
      #pragma unroll
      for (int mi = 0; mi < 4; ++mi)
        #pragma unroll
        for (int ni = 0; ni < 4; ++ni)
          acc[mi][ni] = __builtin_amdgcn_mfma_f32_16x16x32_bf16(
              af[mi], bf[ni], acc[mi][ni], 0, 0, 0);
    }
    __syncthreads();
  }

  // Epilogue. C/D layout: col = lane&15, row = quad*4 + reg.
  float sqc[4];
  int lc[4];
  #pragma unroll
  for (int ni = 0; ni < 4; ++ni) {
    const int col = colBase + waveN * 64 + ni * 16 + l16;
    sqc[ni] = sq[col];
    lc[ni] = labels[col];
  }

  float ncp[4] = {0.f, 0.f, 0.f, 0.f};  // col-sum partials (off-diag only)
  float dcp[4] = {0.f, 0.f, 0.f, 0.f};

  #pragma unroll
  for (int mi = 0; mi < 4; ++mi) {
    const int rbase = rowBase + waveM * 64 + mi * 16 + quad * 4;
    const float4 sqr4 = *(const float4*)(sq + rbase);
    const int4 lr4 = *(const int4*)(labels + rbase);
    const float sqr[4] = {sqr4.x, sqr4.y, sqr4.z, sqr4.w};
    const int lr[4] = {lr4.x, lr4.y, lr4.z, lr4.w};
    #pragma unroll
    for (int r = 0; r < 4; ++r) {
      float np = 0.f, dp = 0.f;
      #pragma unroll
      for (int ni = 0; ni < 4; ++ni) {
        float d2 = fmaxf(fmaf(-2.f, acc[mi][ni][r], sqr[r] + sqc[ni]), EPS);
        float d = __builtin_amdgcn_sqrtf(d2);
        float rc = __builtin_amdgcn_rcpf(d + MARGIN);
        const bool same = (lr[r] == lc[ni]);
        const float dsel = same ? d : 0.f;
        const float rsel = same ? 0.f : rc;
        np += dsel; dp += rsel;
        ncp[ni] += dsel; dcp[ni] += rsel;
      }
      #pragma unroll
      for (int off = 1; off < 16; off <<= 1) {
        np += __shfl_xor(np, off, 64);
        dp += __shfl_xor(dp, off, 64);
      }
      if (l16 == 0) {
        unsafeAtomicAdd(&numv[rbase + r], np);
        unsafeAtomicAdd(&denv[rbase + r], dp);
      }
    }
  }

  if (!diag) {
    #pragma unroll
    for (int ni = 0; ni < 4; ++ni) {
      float n2 = ncp[ni], d2 = dcp[ni];
      n2 += __shfl_xor(n2, 16, 64); d2 += __shfl_xor(d2, 16, 64);
      n2 += __shfl_xor(n2, 32, 64); d2 += __shfl_xor(d2, 32, 64);
      if (quad == 0) {
        const int col = colBase + waveN * 64 + ni * 16 + l16;
        unsafeAtomicAdd(&numv[col], n2);
        unsafeAtomicAdd(&denv[col], d2);
      }
    }
  }
}

// --- Kernel 3a: S = sum_a num[a]*den[a] (32 blocks, f64 atomic) --------------
__global__ __launch_bounds__(256) void fin1_kernel(
    const float* __restrict__ numv, const float* __restrict__ denv,
    double* __restrict__ Ssum)
{
  const int a = blockIdx.x * 256 + threadIdx.x;
  const int lane = threadIdx.x & 63;
  const int wave = threadIdx.x >> 6;
  double s = (double)numv[a] * (double)denv[a];
  #pragma unroll
  for (int off = 32; off > 0; off >>= 1) s += __shfl_down(s, off, 64);
  __shared__ double sh[4];
  if (lane == 0) sh[wave] = s;
  __syncthreads();
  if (threadIdx.x == 0) unsafeAtomicAdd(Ssum, sh[0] + sh[1] + sh[2] + sh[3]);
}

// --- Kernel 3b: out = S / sum_k c_k^2 (N - c_k) -------------------------------
__global__ __launch_bounds__(64) void fin2_kernel(
    const double* __restrict__ Ssum, const int* __restrict__ cnt,
    float* __restrict__ out)
{
  double m = 0.0;
  for (int c = threadIdx.x; c < NUM_CLASSES; c += 64) {
    const double cc = (double)cnt[c];
    m += cc * cc * (double)(N - cc);
  }
  #pragma unroll
  for (int off = 32; off > 0; off >>= 1) m += __shfl_down(m, off, 64);
  if (threadIdx.x == 0) out[0] = (float)(Ssum[0] / m);
}

extern "C" void kernel_launch(void* const* d_in, const int* in_sizes, int n_in,
                              void* d_out, int out_size, void* d_ws, size_t ws_size,
                              hipStream_t stream) {
  const float* emb = (const float*)d_in[0];
  const int* labels = (const int*)d_in[1];
  float* out = (float*)d_out;

  // ws layout: Ebf[N*E bf16] | sq[N] | numv[N] | denv[N] | cnt[128] | Ssum[1 f64]
  char* w = (char*)d_ws;
  __hip_bfloat16* Ebf = (__hip_bfloat16*)w;
  float* sq = (float*)(w + (size_t)N * E * 2);
  float* numv = sq + N;
  float* denv = numv + N;
  int* cnt = (int*)(denv + N);
  double* Ssum = (double*)(cnt + 128);

  // zero numv/denv/cnt/Ssum (ws is re-poisoned 0xAA before every call)
  hipMemsetAsync(numv, 0, (size_t)(2 * N) * sizeof(float) + 128 * sizeof(int) + sizeof(double),
                 stream);

  prep_kernel<<<N / 16, 256, 0, stream>>>(emb, labels, Ebf, sq, cnt);
  gram_kernel<<<dim3(N / BN, N / BM), 256, 0, stream>>>(Ebf, sq, labels, numv, denv);
  fin1_kernel<<<N / 256, 256, 0, stream>>>(numv, denv, Ssum);
  fin2_kernel<<<1, 64, 0, stream>>>(Ssum, cnt, out);
}

// Round 3
// 194.820 us; speedup vs baseline: 1.3136x; 1.0130x over previous
//
#include <hip/hip_runtime.h>
#include <hip/hip_bf16.h>
#include <stdint.h>

#define N 8192
#define E 256
#define NUM_CLASSES 100
#define MARGIN 0.1f
#define EPS 1e-4f

#define BT 64            // tile dim (both M and N of a Gram tile)
#define BK 64            // k-slab per stage
#define MT (N / BT)      // 128 tile-rows -> 128*129/2 = 8256 upper-tri tiles
#define NTILES (MT * (MT + 1) / 2)
#define E_BYTES (E * 2)  // bf16 row = 512 B

typedef __attribute__((ext_vector_type(8))) short short8;   // 8 bf16 (4 VGPRs)
typedef __attribute__((ext_vector_type(4))) float floatx4;  // MFMA C/D

typedef const __attribute__((address_space(1))) void* gptr_t;
typedef __attribute__((address_space(3))) void* sptr_t;

// --- Kernel 1: bf16 cast + row norms + zero the accumulators -----------------
// 512 blocks x 256 threads; each wave handles 4 rows (float4/lane). Each block
// also zeros its 16 rows of numv/denv (replaces the hipMemsetAsync dispatch).
__global__ __launch_bounds__(256) void prep_kernel(
    const float* __restrict__ emb, __hip_bfloat16* __restrict__ Ebf,
    float* __restrict__ sq, float* __restrict__ numv, float* __restrict__ denv)
{
  const int lane = threadIdx.x & 63;
  const int wave = threadIdx.x >> 6;
  const int rb = blockIdx.x * 16;
  if (threadIdx.x < 16) {
    numv[rb + threadIdx.x] = 0.f;
    denv[rb + threadIdx.x] = 0.f;
  }
  #pragma unroll
  for (int i = 0; i < 4; ++i) {
    const int row = rb + i * 4 + wave;
    const float4 x = *(const float4*)(emb + (size_t)row * E + lane * 4);
    union { __hip_bfloat16 h[4]; ushort4 u; } pk;
    pk.h[0] = __float2bfloat16(x.x);
    pk.h[1] = __float2bfloat16(x.y);
    pk.h[2] = __float2bfloat16(x.z);
    pk.h[3] = __float2bfloat16(x.w);
    *(ushort4*)((unsigned short*)Ebf + (size_t)row * E + lane * 4) = pk.u;
    float s = x.x * x.x + x.y * x.y + x.z * x.z + x.w * x.w;
    #pragma unroll
    for (int off = 32; off > 0; off >>= 1) s += __shfl_down(s, off, 64);
    if (lane == 0) sq[row] = s;
  }
}

// --- Kernel 2: 64x64-tile bf16 MFMA Gram, triangular grid, fused epilogue ----
// Linear grid over the 8256 upper-triangle tiles (no dead blocks). 4 waves,
// each computing a 32x32 sub-tile via 2x2 MFMA 16x16x32 => 16 AGPR/wave, small
// VGPR footprint -> __launch_bounds__(256,4) targets 4 waves/SIMD (50% occ).
// Off-diagonal tiles accumulate row-sums AND (by symmetry) col-sums.
// LDS XOR-swizzle (proved conflict-free in R2): chunk c holds (row c>>3,
// k-chunk (c&7)^(r&7)); global_load_lds dest stays linear (HW constraint).
__global__ __launch_bounds__(256, 4) void gram_kernel(
    const __hip_bfloat16* __restrict__ Ebf, const float* __restrict__ sq,
    const int* __restrict__ labels, float* __restrict__ numv, float* __restrict__ denv)
{
  // decode linear tile id -> (by, bx), bx >= by. S(b) = b*MT - b*(b-1)/2.
  const int t = blockIdx.x;
  int by = (int)((2.0 * MT + 1.0 - __builtin_sqrt((2.0 * MT + 1.0) * (2.0 * MT + 1.0) - 8.0 * t)) * 0.5);
  while (by * MT - by * (by - 1) / 2 > t) --by;
  while ((by + 1) * MT - (by + 1) * by / 2 <= t) ++by;
  const int bx = by + (t - (by * MT - by * (by - 1) / 2));
  const bool diag = (bx == by);

  __shared__ alignas(16) __hip_bfloat16 As[BT * BK];  // 8 KB
  __shared__ alignas(16) __hip_bfloat16 Bs[BT * BK];  // 8 KB

  const int tid = threadIdx.x;
  const int lane = tid & 63;
  const int wave = tid >> 6;
  const int waveM = wave >> 1;
  const int waveN = wave & 1;
  const int quad = lane >> 4;
  const int l16 = lane & 15;

  const int rowBase = by * BT;
  const int colBase = bx * BT;

  floatx4 acc[2][2];
  #pragma unroll
  for (int i = 0; i < 2; ++i)
    #pragma unroll
    for (int j = 0; j < 2; ++j)
      acc[i][j] = (floatx4){0.f, 0.f, 0.f, 0.f};

  const char* gbase = (const char*)Ebf;

  for (int k0 = 0; k0 < E; k0 += BK) {
    // Stage 8 KB per tile = 2 rounds x 256 threads x 16 B, swizzled source.
    #pragma unroll
    for (int it = 0; it < 2; ++it) {
      const int c = it * 256 + tid;       // chunk 0..511
      const int r = c >> 3;               // tile row (128-B k-rows, 8 chunks)
      const int kq = (c & 7) ^ (r & 7);   // swizzled k-chunk
      const int srcoff = k0 * 2 + kq * 16;
      const int dstoff = c * 16;
      const char* gA = gbase + (size_t)(rowBase + r) * E_BYTES + srcoff;
      __builtin_amdgcn_global_load_lds((gptr_t)gA, (sptr_t)((char*)As + dstoff), 16, 0, 0);
      if (!diag) {
        const char* gB = gbase + (size_t)(colBase + r) * E_BYTES + srcoff;
        __builtin_amdgcn_global_load_lds((gptr_t)gB, (sptr_t)((char*)Bs + dstoff), 16, 0, 0);
      }
    }
    __syncthreads();

    const __hip_bfloat16* Bsrc = diag ? As : Bs;
    #pragma unroll
    for (int ks = 0; ks < 2; ++ks) {  // two K=32 MFMA steps per BK=64 stage
      const int q = ks * 4 + quad;
      short8 af[2], bf[2];
      #pragma unroll
      for (int mi = 0; mi < 2; ++mi) {
        const int r = waveM * 32 + mi * 16 + l16;
        af[mi] = *(const short8*)((const char*)As + (r * 8 + (q ^ (r & 7))) * 16);
      }
      #pragma unroll
      for (int ni = 0; ni < 2; ++ni) {
        const int r = waveN * 32 + ni * 16 + l16;
        bf[ni] = *(const short8*)((const char*)Bsrc + (r * 8 + (q ^ (r & 7))) * 16);
      }
      #pragma unroll
      for (int mi = 0; mi < 2; ++mi)
        #pragma unroll
        for (int ni = 0; ni < 2; ++ni)
          acc[mi][ni] = __builtin_amdgcn_mfma_f32_16x16x32_bf16(
              af[mi], bf[ni], acc[mi][ni], 0, 0, 0);
    }
    __syncthreads();
  }

  // Epilogue. C/D layout: col = lane&15, row = quad*4 + reg.
  float sqc[2];
  int lc[2];
  #pragma unroll
  for (int ni = 0; ni < 2; ++ni) {
    const int col = colBase + waveN * 32 + ni * 16 + l16;
    sqc[ni] = sq[col];
    lc[ni] = labels[col];
  }

  float ncp[2] = {0.f, 0.f};  // col-sum partials (used off-diag)
  float dcp[2] = {0.f, 0.f};

  #pragma unroll
  for (int mi = 0; mi < 2; ++mi) {
    const int rbase = rowBase + waveM * 32 + mi * 16 + quad * 4;
    const float4 sqr4 = *(const float4*)(sq + rbase);
    const int4 lr4 = *(const int4*)(labels + rbase);
    const float sqr[4] = {sqr4.x, sqr4.y, sqr4.z, sqr4.w};
    const int lr[4] = {lr4.x, lr4.y, lr4.z, lr4.w};
    #pragma unroll
    for (int r = 0; r < 4; ++r) {
      float np = 0.f, dp = 0.f;
      #pragma unroll
      for (int ni = 0; ni < 2; ++ni) {
        float d2 = fmaxf(fmaf(-2.f, acc[mi][ni][r], sqr[r] + sqc[ni]), EPS);
        float d = __builtin_amdgcn_sqrtf(d2);
        float rc = __builtin_amdgcn_rcpf(d + MARGIN);
        const bool same = (lr[r] == lc[ni]);
        const float dsel = same ? d : 0.f;
        const float rsel = same ? 0.f : rc;
        np += dsel; dp += rsel;
        ncp[ni] += dsel; dcp[ni] += rsel;
      }
      #pragma unroll
      for (int off = 1; off < 16; off <<= 1) {
        np += __shfl_xor(np, off, 64);
        dp += __shfl_xor(dp, off, 64);
      }
      if (l16 == 0) {
        unsafeAtomicAdd(&numv[rbase + r], np);
        unsafeAtomicAdd(&denv[rbase + r], dp);
      }
    }
  }

  if (!diag) {
    #pragma unroll
    for (int ni = 0; ni < 2; ++ni) {
      float n2 = ncp[ni], d2 = dcp[ni];
      n2 += __shfl_xor(n2, 16, 64); d2 += __shfl_xor(d2, 16, 64);
      n2 += __shfl_xor(n2, 32, 64); d2 += __shfl_xor(d2, 32, 64);
      if (quad == 0) {
        const int col = colBase + waveN * 32 + ni * 16 + l16;
        unsafeAtomicAdd(&numv[col], n2);
        unsafeAtomicAdd(&denv[col], d2);
      }
    }
  }
}

// --- Kernel 3a: per-block partials of S = sum_a num[a]*den[a] (no atomics) ---
__global__ __launch_bounds__(256) void fin1_kernel(
    const float* __restrict__ numv, const float* __restrict__ denv,
    double* __restrict__ partials)
{
  const int a = blockIdx.x * 256 + threadIdx.x;
  const int lane = threadIdx.x & 63;
  const int wave = threadIdx.x >> 6;
  double s = (double)numv[a] * (double)denv[a];
  #pragma unroll
  for (int off = 32; off > 0; off >>= 1) s += __shfl_down(s, off, 64);
  __shared__ double sh[4];
  if (lane == 0) sh[wave] = s;
  __syncthreads();
  if (threadIdx.x == 0) partials[blockIdx.x] = sh[0] + sh[1] + sh[2] + sh[3];
}

// --- Kernel 3b: label histogram + m_sum + final divide (1 block) -------------
__global__ __launch_bounds__(256) void fin2_kernel(
    const double* __restrict__ partials, const int* __restrict__ labels,
    float* __restrict__ out)
{
  __shared__ int hist[NUM_CLASSES];
  __shared__ double shm[4], shs[4];
  const int tid = threadIdx.x;
  const int lane = tid & 63;
  const int wave = tid >> 6;
  if (tid < NUM_CLASSES) hist[tid] = 0;
  __syncthreads();
  for (int a = tid; a < N; a += 256) atomicAdd(&hist[labels[a]], 1);
  __syncthreads();
  double m = 0.0;
  if (tid < NUM_CLASSES) {
    const double cc = (double)hist[tid];
    m = cc * cc * (double)(N - cc);
  }
  double s = (tid < 32) ? partials[tid] : 0.0;
  #pragma unroll
  for (int off = 32; off > 0; off >>= 1) {
    m += __shfl_down(m, off, 64);
    s += __shfl_down(s, off, 64);
  }
  if (lane == 0) { shm[wave] = m; shs[wave] = s; }
  __syncthreads();
  if (tid == 0) {
    const double M = shm[0] + shm[1] + shm[2] + shm[3];
    const double S = shs[0] + shs[1] + shs[2] + shs[3];
    out[0] = (float)(S / M);
  }
}

extern "C" void kernel_launch(void* const* d_in, const int* in_sizes, int n_in,
                              void* d_out, int out_size, void* d_ws, size_t ws_size,
                              hipStream_t stream) {
  const float* emb = (const float*)d_in[0];
  const int* labels = (const int*)d_in[1];
  float* out = (float*)d_out;

  // ws layout: Ebf[N*E bf16] | sq[N] | numv[N] | denv[N] | partials[32 f64]
  char* w = (char*)d_ws;
  __hip_bfloat16* Ebf = (__hip_bfloat16*)w;
  float* sq = (float*)(w + (size_t)N * E * 2);
  float* numv = sq + N;
  float* denv = numv + N;
  double* partials = (double*)(denv + N);

  prep_kernel<<<N / 16, 256, 0, stream>>>(emb, Ebf, sq, numv, denv);
  gram_kernel<<<NTILES, 256, 0, stream>>>(Ebf, sq, labels, numv, denv);
  fin1_kernel<<<N / 256, 256, 0, stream>>>(numv, denv, partials);
  fin2_kernel<<<1, 256, 0, stream>>>(partials, labels, out);
}

// Round 4
// 131.912 us; speedup vs baseline: 1.9400x; 1.4769x over previous
//
#include <hip/hip_runtime.h>
#include <hip/hip_bf16.h>
#include <stdint.h>

#define N 8192
#define E 256
#define NUM_CLASSES 100
#define MARGIN 0.1f
#define EPS 1e-4f

#define BT 64            // tile dim
#define BK 64            // k-slab per stage
#define MT (N / BT)      // 128 tile-rows -> 8256 upper-tri tiles
#define NTILES (MT * (MT + 1) / 2)
#define E_BYTES (E * 2)  // bf16 row = 512 B
#define FIN_BLOCKS (N / 256)  // 32

typedef __attribute__((ext_vector_type(8))) short short8;   // 8 bf16 (4 VGPRs)
typedef __attribute__((ext_vector_type(4))) float floatx4;  // MFMA C/D

typedef const __attribute__((address_space(1))) void* gptr_t;
typedef __attribute__((address_space(3))) void* sptr_t;

// --- Kernel 1: bf16 cast + row norms; block 0 zeroes Ssum/counter ------------
__global__ __launch_bounds__(256) void prep_kernel(
    const float* __restrict__ emb, __hip_bfloat16* __restrict__ Ebf,
    float* __restrict__ sq, double* __restrict__ Ssum, int* __restrict__ counter)
{
  const int lane = threadIdx.x & 63;
  const int wave = threadIdx.x >> 6;
  if (blockIdx.x == 0 && threadIdx.x == 0) {
    *Ssum = 0.0;
    *counter = 0;
  }
  #pragma unroll
  for (int i = 0; i < 4; ++i) {
    const int row = blockIdx.x * 16 + i * 4 + wave;
    const float4 x = *(const float4*)(emb + (size_t)row * E + lane * 4);
    union { __hip_bfloat16 h[4]; ushort4 u; } pk;
    pk.h[0] = __float2bfloat16(x.x);
    pk.h[1] = __float2bfloat16(x.y);
    pk.h[2] = __float2bfloat16(x.z);
    pk.h[3] = __float2bfloat16(x.w);
    *(ushort4*)((unsigned short*)Ebf + (size_t)row * E + lane * 4) = pk.u;
    float s = x.x * x.x + x.y * x.y + x.z * x.z + x.w * x.w;
    #pragma unroll
    for (int off = 32; off > 0; off >>= 1) s += __shfl_down(s, off, 64);
    if (lane == 0) sq[row] = s;
  }
}

// --- Kernel 2: 64x64-tile bf16 MFMA Gram, triangular grid, ATOMIC-FREE -------
// part[k][a] has a unique writer: tile (by,bx) writes row-sums to
// part[bx][by*64+r] and (off-diag) col-sums to part[by][bx*64+c]. Every (k,a)
// covered exactly once => plain stores, no init, no atomics. Cross-wave
// combining (two waves share each row / each col) goes through 1 KB LDS.
__global__ __launch_bounds__(256, 4) void gram_kernel(
    const __hip_bfloat16* __restrict__ Ebf, const float* __restrict__ sq,
    const int* __restrict__ labels, float* __restrict__ numpart,
    float* __restrict__ denpart)
{
  // decode linear tile id -> (by, bx), bx >= by
  const int t = blockIdx.x;
  int by = (int)((2.0 * MT + 1.0 - __builtin_sqrt((2.0 * MT + 1.0) * (2.0 * MT + 1.0) - 8.0 * t)) * 0.5);
  while (by * MT - by * (by - 1) / 2 > t) --by;
  while ((by + 1) * MT - (by + 1) * by / 2 <= t) ++by;
  const int bx = by + (t - (by * MT - by * (by - 1) / 2));
  const bool diag = (bx == by);

  __shared__ alignas(16) __hip_bfloat16 As[BT * BK];  // 8 KB
  __shared__ alignas(16) __hip_bfloat16 Bs[BT * BK];  // 8 KB
  __shared__ float rnum[64], rden[64], cnum[64], cden[64];  // 1 KB

  const int tid = threadIdx.x;
  const int lane = tid & 63;
  const int wave = tid >> 6;
  const int waveM = wave >> 1;
  const int waveN = wave & 1;
  const int quad = lane >> 4;
  const int l16 = lane & 15;

  const int rowBase = by * BT;
  const int colBase = bx * BT;

  floatx4 acc[2][2];
  #pragma unroll
  for (int i = 0; i < 2; ++i)
    #pragma unroll
    for (int j = 0; j < 2; ++j)
      acc[i][j] = (floatx4){0.f, 0.f, 0.f, 0.f};

  const char* gbase = (const char*)Ebf;

  for (int k0 = 0; k0 < E; k0 += BK) {
    #pragma unroll
    for (int it = 0; it < 2; ++it) {
      const int c = it * 256 + tid;       // chunk 0..511
      const int r = c >> 3;               // tile row (128-B k-rows, 8 chunks)
      const int kq = (c & 7) ^ (r & 7);   // swizzled k-chunk (conflict-free)
      const int srcoff = k0 * 2 + kq * 16;
      const int dstoff = c * 16;
      const char* gA = gbase + (size_t)(rowBase + r) * E_BYTES + srcoff;
      __builtin_amdgcn_global_load_lds((gptr_t)gA, (sptr_t)((char*)As + dstoff), 16, 0, 0);
      if (!diag) {
        const char* gB = gbase + (size_t)(colBase + r) * E_BYTES + srcoff;
        __builtin_amdgcn_global_load_lds((gptr_t)gB, (sptr_t)((char*)Bs + dstoff), 16, 0, 0);
      }
    }
    __syncthreads();

    const __hip_bfloat16* Bsrc = diag ? As : Bs;
    #pragma unroll
    for (int ks = 0; ks < 2; ++ks) {
      const int q = ks * 4 + quad;
      short8 af[2], bf[2];
      #pragma unroll
      for (int mi = 0; mi < 2; ++mi) {
        const int r = waveM * 32 + mi * 16 + l16;
        af[mi] = *(const short8*)((const char*)As + (r * 8 + (q ^ (r & 7))) * 16);
      }
      #pragma unroll
      for (int ni = 0; ni < 2; ++ni) {
        const int r = waveN * 32 + ni * 16 + l16;
        bf[ni] = *(const short8*)((const char*)Bsrc + (r * 8 + (q ^ (r & 7))) * 16);
      }
      #pragma unroll
      for (int mi = 0; mi < 2; ++mi)
        #pragma unroll
        for (int ni = 0; ni < 2; ++ni)
          acc[mi][ni] = __builtin_amdgcn_mfma_f32_16x16x32_bf16(
              af[mi], bf[ni], acc[mi][ni], 0, 0, 0);
    }
    __syncthreads();
  }

  // Epilogue. C/D layout: col = lane&15, row = quad*4 + reg.
  float sqc[2];
  int lc[2];
  #pragma unroll
  for (int ni = 0; ni < 2; ++ni) {
    const int col = colBase + waveN * 32 + ni * 16 + l16;
    sqc[ni] = sq[col];
    lc[ni] = labels[col];
  }

  float ncp[2] = {0.f, 0.f};
  float dcp[2] = {0.f, 0.f};
  float npv[2][4], dpv[2][4];

  #pragma unroll
  for (int mi = 0; mi < 2; ++mi) {
    const int rbase = rowBase + waveM * 32 + mi * 16 + quad * 4;
    const float4 sqr4 = *(const float4*)(sq + rbase);
    const int4 lr4 = *(const int4*)(labels + rbase);
    const float sqr[4] = {sqr4.x, sqr4.y, sqr4.z, sqr4.w};
    const int lr[4] = {lr4.x, lr4.y, lr4.z, lr4.w};
    #pragma unroll
    for (int r = 0; r < 4; ++r) {
      float np = 0.f, dp = 0.f;
      #pragma unroll
      for (int ni = 0; ni < 2; ++ni) {
        float d2 = fmaxf(fmaf(-2.f, acc[mi][ni][r], sqr[r] + sqc[ni]), EPS);
        float d = __builtin_amdgcn_sqrtf(d2);
        float rc = __builtin_amdgcn_rcpf(d + MARGIN);
        const bool same = (lr[r] == lc[ni]);
        const float dsel = same ? d : 0.f;
        const float rsel = same ? 0.f : rc;
        np += dsel; dp += rsel;
        ncp[ni] += dsel; dcp[ni] += rsel;
      }
      // reduce over the 16 lanes sharing this row
      #pragma unroll
      for (int off = 1; off < 16; off <<= 1) {
        np += __shfl_xor(np, off, 64);
        dp += __shfl_xor(dp, off, 64);
      }
      npv[mi][r] = np;
      dpv[mi][r] = dp;
    }
  }

  // col partials: reduce over quads (rows) within the wave
  float n2r[2], d2r[2];
  #pragma unroll
  for (int ni = 0; ni < 2; ++ni) {
    float n2 = ncp[ni], d2 = dcp[ni];
    n2 += __shfl_xor(n2, 16, 64); d2 += __shfl_xor(d2, 16, 64);
    n2 += __shfl_xor(n2, 32, 64); d2 += __shfl_xor(d2, 32, 64);
    n2r[ni] = n2; d2r[ni] = d2;
  }

  // stage one wave-half in LDS, combine in the other, plain global stores
  if (waveN == 0 && l16 == 0) {
    #pragma unroll
    for (int mi = 0; mi < 2; ++mi)
      #pragma unroll
      for (int r = 0; r < 4; ++r) {
        const int idx = waveM * 32 + mi * 16 + quad * 4 + r;
        rnum[idx] = npv[mi][r];
        rden[idx] = dpv[mi][r];
      }
  }
  if (!diag && waveM == 0 && quad == 0) {
    #pragma unroll
    for (int ni = 0; ni < 2; ++ni) {
      const int idx = waveN * 32 + ni * 16 + l16;
      cnum[idx] = n2r[ni];
      cden[idx] = d2r[ni];
    }
  }
  __syncthreads();

  if (waveN == 1 && l16 == 0) {
    #pragma unroll
    for (int mi = 0; mi < 2; ++mi) {
      const int idx0 = waveM * 32 + mi * 16 + quad * 4;
      float4 nv, dv;
      nv.x = npv[mi][0] + rnum[idx0 + 0];
      nv.y = npv[mi][1] + rnum[idx0 + 1];
      nv.z = npv[mi][2] + rnum[idx0 + 2];
      nv.w = npv[mi][3] + rnum[idx0 + 3];
      dv.x = dpv[mi][0] + rden[idx0 + 0];
      dv.y = dpv[mi][1] + rden[idx0 + 1];
      dv.z = dpv[mi][2] + rden[idx0 + 2];
      dv.w = dpv[mi][3] + rden[idx0 + 3];
      *(float4*)(numpart + (size_t)bx * N + rowBase + idx0) = nv;
      *(float4*)(denpart + (size_t)bx * N + rowBase + idx0) = dv;
    }
  }
  if (!diag && waveM == 1 && quad == 0) {
    #pragma unroll
    for (int ni = 0; ni < 2; ++ni) {
      const int idx = waveN * 32 + ni * 16 + l16;
      numpart[(size_t)by * N + colBase + idx] = n2r[ni] + cnum[idx];
      denpart[(size_t)by * N + colBase + idx] = d2r[ni] + cden[idx];
    }
  }
}

// --- Kernel 3: fold partials, S-reduce, last block does m_sum + divide -------
__global__ __launch_bounds__(256) void fin_kernel(
    const float* __restrict__ numpart, const float* __restrict__ denpart,
    const int* __restrict__ labels, double* __restrict__ Ssum,
    int* __restrict__ counter, float* __restrict__ out)
{
  __shared__ double sh[4];
  __shared__ int lastflag;
  __shared__ int hist[NUM_CLASSES];
  __shared__ double shm[4];

  const int tid = threadIdx.x;
  const int lane = tid & 63;
  const int wave = tid >> 6;
  const int a = blockIdx.x * 256 + tid;

  float np = 0.f, dp = 0.f;
  #pragma unroll 4
  for (int k = 0; k < MT; ++k) {
    np += numpart[(size_t)k * N + a];
    dp += denpart[(size_t)k * N + a];
  }
  double s = (double)np * (double)dp;
  #pragma unroll
  for (int off = 32; off > 0; off >>= 1) s += __shfl_down(s, off, 64);
  if (lane == 0) sh[wave] = s;
  __syncthreads();
  if (tid == 0) {
    unsafeAtomicAdd(Ssum, sh[0] + sh[1] + sh[2] + sh[3]);
    __threadfence();
    const int prev = __hip_atomic_fetch_add(counter, 1, __ATOMIC_ACQ_REL,
                                            __HIP_MEMORY_SCOPE_AGENT);
    lastflag = (prev == FIN_BLOCKS - 1) ? 1 : 0;
  }
  __syncthreads();

  if (lastflag) {
    if (tid < NUM_CLASSES) hist[tid] = 0;
    __syncthreads();
    for (int i = tid; i < N; i += 256) atomicAdd(&hist[labels[i]], 1);
    __syncthreads();
    double m = 0.0;
    if (tid < NUM_CLASSES) {
      const double cc = (double)hist[tid];
      m = cc * cc * (double)(N - cc);
    }
    #pragma unroll
    for (int off = 32; off > 0; off >>= 1) m += __shfl_down(m, off, 64);
    if (lane == 0) shm[wave] = m;
    __syncthreads();
    if (tid == 0) {
      const double M = shm[0] + shm[1] + shm[2] + shm[3];
      const double S = __hip_atomic_load(Ssum, __ATOMIC_RELAXED,
                                         __HIP_MEMORY_SCOPE_AGENT);
      out[0] = (float)(S / M);
    }
  }
}

extern "C" void kernel_launch(void* const* d_in, const int* in_sizes, int n_in,
                              void* d_out, int out_size, void* d_ws, size_t ws_size,
                              hipStream_t stream) {
  const float* emb = (const float*)d_in[0];
  const int* labels = (const int*)d_in[1];
  float* out = (float*)d_out;

  // ws: Ebf[4MB] | sq[32KB] | numpart[4MB] | denpart[4MB] | Ssum[8B] | counter
  char* w = (char*)d_ws;
  __hip_bfloat16* Ebf = (__hip_bfloat16*)w;
  float* sq = (float*)(w + (size_t)N * E * 2);
  float* numpart = sq + N;
  float* denpart = numpart + (size_t)MT * N;
  double* Ssum = (double*)(denpart + (size_t)MT * N);
  int* counter = (int*)(Ssum + 1);

  prep_kernel<<<N / 16, 256, 0, stream>>>(emb, Ebf, sq, Ssum, counter);
  gram_kernel<<<NTILES, 256, 0, stream>>>(Ebf, sq, labels, numpart, denpart);
  fin_kernel<<<FIN_BLOCKS, 256, 0, stream>>>(numpart, denpart, labels, Ssum,
                                             counter, out);
}

// Round 5
// 128.466 us; speedup vs baseline: 1.9921x; 1.0268x over previous
//
#include <hip/hip_runtime.h>
#include <hip/hip_bf16.h>
#include <stdint.h>

#define N 8192
#define E 256
#define NUM_CLASSES 100
#define MARGIN 0.1f
#define EPS 1e-4f

#define BT 128           // tile dim (M and N of a Gram tile)
#define BK 64            // k-slab per stage (128 B per row)
#define MT (N / BT)      // 64 tile-rows -> 64*65/2 = 2080 upper-tri tiles
#define NTILES (MT * (MT + 1) / 2)
#define E_BYTES (E * 2)  // bf16 row = 512 B
#define FIN_BLOCKS (N / 256)  // 32

typedef __attribute__((ext_vector_type(8))) short short8;   // 8 bf16 (4 VGPRs)
typedef __attribute__((ext_vector_type(4))) float floatx4;  // MFMA C/D

typedef const __attribute__((address_space(1))) void* gptr_t;
typedef __attribute__((address_space(3))) void* sptr_t;

// 16-lane butterfly sum on the VALU via DPP (no LDS-pipe usage, unlike shfl).
// quad_perm[1,0,3,2]=0xB1 (xor1), quad_perm[2,3,0,1]=0x4E (xor2),
// row_half_mirror=0x141 (sum-of-8), row_mirror=0x140 (sum-of-16).
__device__ __forceinline__ float dpp_sum16(float v) {
  v += __int_as_float(__builtin_amdgcn_update_dpp(0, __float_as_int(v), 0xB1, 0xF, 0xF, true));
  v += __int_as_float(__builtin_amdgcn_update_dpp(0, __float_as_int(v), 0x4E, 0xF, 0xF, true));
  v += __int_as_float(__builtin_amdgcn_update_dpp(0, __float_as_int(v), 0x141, 0xF, 0xF, true));
  v += __int_as_float(__builtin_amdgcn_update_dpp(0, __float_as_int(v), 0x140, 0xF, 0xF, true));
  return v;
}

// --- Kernel 1: bf16 cast + row norms; block 0 zeroes Ssum/counter ------------
__global__ __launch_bounds__(256) void prep_kernel(
    const float* __restrict__ emb, __hip_bfloat16* __restrict__ Ebf,
    float* __restrict__ sq, double* __restrict__ Ssum, int* __restrict__ counter)
{
  const int lane = threadIdx.x & 63;
  const int wave = threadIdx.x >> 6;
  if (blockIdx.x == 0 && threadIdx.x == 0) {
    *Ssum = 0.0;
    *counter = 0;
  }
  #pragma unroll
  for (int i = 0; i < 4; ++i) {
    const int row = blockIdx.x * 16 + i * 4 + wave;
    const float4 x = *(const float4*)(emb + (size_t)row * E + lane * 4);
    union { __hip_bfloat16 h[4]; ushort4 u; } pk;
    pk.h[0] = __float2bfloat16(x.x);
    pk.h[1] = __float2bfloat16(x.y);
    pk.h[2] = __float2bfloat16(x.z);
    pk.h[3] = __float2bfloat16(x.w);
    *(ushort4*)((unsigned short*)Ebf + (size_t)row * E + lane * 4) = pk.u;
    float s = x.x * x.x + x.y * x.y + x.z * x.z + x.w * x.w;
    #pragma unroll
    for (int off = 32; off > 0; off >>= 1) s += __shfl_down(s, off, 64);
    if (lane == 0) sq[row] = s;
  }
}

// --- Kernel 2: 128x128-tile bf16 MFMA Gram, triangular grid, atomic-free -----
// 4 waves in 2x2; each wave owns a 64x64 subtile = 4x4 MFMA 16x16x32 (64 AGPR).
// 1 ds_read_b128 feeds 2 MFMAs (vs 1:1 at 64-tiles) -> halves LDS frag traffic.
// Epilogue: per-mi streamed; 16-lane row reduce via DPP (VALU pipe), cross-wave
// combine via ds_add_f32 into 2 KB LDS accumulators, then coalesced stores to
// the unique-writer partials (tile(by,bx): rows->part[bx], cols->part[by]).
__global__ __launch_bounds__(256, 2) void gram_kernel(
    const __hip_bfloat16* __restrict__ Ebf, const float* __restrict__ sq,
    const int* __restrict__ labels, float* __restrict__ numpart,
    float* __restrict__ denpart)
{
  // decode linear tile id -> (by, bx), bx >= by
  const int t = blockIdx.x;
  int by = (int)((2.0 * MT + 1.0 - __builtin_sqrt((2.0 * MT + 1.0) * (2.0 * MT + 1.0) - 8.0 * t)) * 0.5);
  while (by * MT - by * (by - 1) / 2 > t) --by;
  while ((by + 1) * MT - (by + 1) * by / 2 <= t) ++by;
  const int bx = by + (t - (by * MT - by * (by - 1) / 2));
  const bool diag = (bx == by);

  __shared__ alignas(16) __hip_bfloat16 As[BT * BK];  // 16 KB
  __shared__ alignas(16) __hip_bfloat16 Bs[BT * BK];  // 16 KB
  __shared__ float redAcc[512];  // rnum|rden|cnum|cden, 128 each (2 KB)
  float* const rnum = redAcc;
  float* const rden = redAcc + 128;
  float* const cnum = redAcc + 256;
  float* const cden = redAcc + 384;

  const int tid = threadIdx.x;
  const int lane = tid & 63;
  const int wave = tid >> 6;
  const int waveM = wave >> 1;
  const int waveN = wave & 1;
  const int quad = lane >> 4;
  const int l16 = lane & 15;

  const int rowBase = by * BT;
  const int colBase = bx * BT;

  // zero the reduction accumulators (visible after first stage barrier)
  redAcc[tid] = 0.f;
  redAcc[tid + 256] = 0.f;

  floatx4 acc[4][4];
  #pragma unroll
  for (int i = 0; i < 4; ++i)
    #pragma unroll
    for (int j = 0; j < 4; ++j)
      acc[i][j] = (floatx4){0.f, 0.f, 0.f, 0.f};

  const char* gbase = (const char*)Ebf;

  for (int k0 = 0; k0 < E; k0 += BK) {
    // Stage 16 KB per tile = 4 rounds x 256 threads x 16 B, XOR-swizzled src:
    // chunk c holds (row r=c>>3, k-chunk (c&7)^(r&7)) -> conflict-free frag reads.
    #pragma unroll
    for (int it = 0; it < 4; ++it) {
      const int c = it * 256 + tid;       // chunk 0..1023
      const int r = c >> 3;               // tile row (128-B k-rows, 8 chunks)
      const int kq = (c & 7) ^ (r & 7);
      const int srcoff = k0 * 2 + kq * 16;
      const int dstoff = c * 16;
      const char* gA = gbase + (size_t)(rowBase + r) * E_BYTES + srcoff;
      __builtin_amdgcn_global_load_lds((gptr_t)gA, (sptr_t)((char*)As + dstoff), 16, 0, 0);
      if (!diag) {
        const char* gB = gbase + (size_t)(colBase + r) * E_BYTES + srcoff;
        __builtin_amdgcn_global_load_lds((gptr_t)gB, (sptr_t)((char*)Bs + dstoff), 16, 0, 0);
      }
    }
    __syncthreads();

    const __hip_bfloat16* Bsrc = diag ? As : Bs;
    #pragma unroll
    for (int ks = 0; ks < 2; ++ks) {
      const int q = ks * 4 + quad;
      short8 af[4], bf[4];
      #pragma unroll
      for (int mi = 0; mi < 4; ++mi) {
        const int r = waveM * 64 + mi * 16 + l16;
        af[mi] = *(const short8*)((const char*)As + (r * 8 + (q ^ (r & 7))) * 16);
      }
      #pragma unroll
      for (int ni = 0; ni < 4; ++ni) {
        const int r = waveN * 64 + ni * 16 + l16;
        bf[ni] = *(const short8*)((const char*)Bsrc + (r * 8 + (q ^ (r & 7))) * 16);
      }
      #pragma unroll
      for (int mi = 0; mi < 4; ++mi)
        #pragma unroll
        for (int ni = 0; ni < 4; ++ni)
          acc[mi][ni] = __builtin_amdgcn_mfma_f32_16x16x32_bf16(
              af[mi], bf[ni], acc[mi][ni], 0, 0, 0);
    }
    __syncthreads();
  }

  // Epilogue. C/D layout: col = lane&15, row = quad*4 + reg.
  float sqc[4];
  int lc[4];
  #pragma unroll
  for (int ni = 0; ni < 4; ++ni) {
    const int col = colBase + waveN * 64 + ni * 16 + l16;
    sqc[ni] = sq[col];
    lc[ni] = labels[col];
  }

  float ncp[4] = {0.f, 0.f, 0.f, 0.f};  // per-lane col partials (fixed col/ni)
  float dcp[4] = {0.f, 0.f, 0.f, 0.f};

  #pragma unroll
  for (int mi = 0; mi < 4; ++mi) {
    const int rbase = rowBase + waveM * 64 + mi * 16 + quad * 4;
    const float4 sqr4 = *(const float4*)(sq + rbase);
    const int4 lr4 = *(const int4*)(labels + rbase);
    const float sqr[4] = {sqr4.x, sqr4.y, sqr4.z, sqr4.w};
    const int lr[4] = {lr4.x, lr4.y, lr4.z, lr4.w};
    float npv[4], dpv[4];
    #pragma unroll
    for (int r = 0; r < 4; ++r) {
      float np = 0.f, dp = 0.f;
      #pragma unroll
      for (int ni = 0; ni < 4; ++ni) {
        float d2 = fmaxf(fmaf(-2.f, acc[mi][ni][r], sqr[r] + sqc[ni]), EPS);
        float d = __builtin_amdgcn_sqrtf(d2);
        float rc = __builtin_amdgcn_rcpf(d + MARGIN);
        const bool same = (lr[r] == lc[ni]);
        const float dsel = same ? d : 0.f;
        const float rsel = same ? 0.f : rc;
        np += dsel; dp += rsel;
        ncp[ni] += dsel; dcp[ni] += rsel;
      }
      npv[r] = dpp_sum16(np);  // all 16 lanes hold the row sum
      dpv[r] = dpp_sum16(dp);
    }
    // lane with l16 == quad*4+r writes row mi*16+l16; select npv[l16&3]
    const float seln = (l16 & 2) ? ((l16 & 1) ? npv[3] : npv[2])
                                 : ((l16 & 1) ? npv[1] : npv[0]);
    const float seld = (l16 & 2) ? ((l16 & 1) ? dpv[3] : dpv[2])
                                 : ((l16 & 1) ? dpv[1] : dpv[0]);
    if ((l16 >> 2) == quad) {
      atomicAdd(&rnum[waveM * 64 + mi * 16 + l16], seln);
      atomicAdd(&rden[waveM * 64 + mi * 16 + l16], seld);
    }
  }

  if (!diag) {
    // 4 quads + 2 waveM waves collide per col address; DS unit serializes.
    #pragma unroll
    for (int ni = 0; ni < 4; ++ni) {
      atomicAdd(&cnum[waveN * 64 + ni * 16 + l16], ncp[ni]);
      atomicAdd(&cden[waveN * 64 + ni * 16 + l16], dcp[ni]);
    }
  }
  __syncthreads();

  // unique-writer global stores (coalesced)
  if (tid < 128) {
    numpart[(size_t)bx * N + rowBase + tid] = rnum[tid];
    denpart[(size_t)bx * N + rowBase + tid] = rden[tid];
  } else if (!diag) {
    const int i = tid - 128;
    numpart[(size_t)by * N + colBase + i] = cnum[i];
    denpart[(size_t)by * N + colBase + i] = cden[i];
  }
}

// --- Kernel 3: fold partials, S-reduce, last block does m_sum + divide -------
__global__ __launch_bounds__(256) void fin_kernel(
    const float* __restrict__ numpart, const float* __restrict__ denpart,
    const int* __restrict__ labels, double* __restrict__ Ssum,
    int* __restrict__ counter, float* __restrict__ out)
{
  __shared__ double sh[4];
  __shared__ int lastflag;
  __shared__ int hist[NUM_CLASSES];
  __shared__ double shm[4];

  const int tid = threadIdx.x;
  const int lane = tid & 63;
  const int wave = tid >> 6;
  const int a = blockIdx.x * 256 + tid;

  float np = 0.f, dp = 0.f;
  #pragma unroll 4
  for (int k = 0; k < MT; ++k) {
    np += numpart[(size_t)k * N + a];
    dp += denpart[(size_t)k * N + a];
  }
  double s = (double)np * (double)dp;
  #pragma unroll
  for (int off = 32; off > 0; off >>= 1) s += __shfl_down(s, off, 64);
  if (lane == 0) sh[wave] = s;
  __syncthreads();
  if (tid == 0) {
    unsafeAtomicAdd(Ssum, sh[0] + sh[1] + sh[2] + sh[3]);
    __threadfence();
    const int prev = __hip_atomic_fetch_add(counter, 1, __ATOMIC_ACQ_REL,
                                            __HIP_MEMORY_SCOPE_AGENT);
    lastflag = (prev == FIN_BLOCKS - 1) ? 1 : 0;
  }
  __syncthreads();

  if (lastflag) {
    if (tid < NUM_CLASSES) hist[tid] = 0;
    __syncthreads();
    for (int i = tid; i < N; i += 256) atomicAdd(&hist[labels[i]], 1);
    __syncthreads();
    double m = 0.0;
    if (tid < NUM_CLASSES) {
      const double cc = (double)hist[tid];
      m = cc * cc * (double)(N - cc);
    }
    #pragma unroll
    for (int off = 32; off > 0; off >>= 1) m += __shfl_down(m, off, 64);
    if (lane == 0) shm[wave] = m;
    __syncthreads();
    if (tid == 0) {
      const double M = shm[0] + shm[1] + shm[2] + shm[3];
      const double S = __hip_atomic_load(Ssum, __ATOMIC_RELAXED,
                                         __HIP_MEMORY_SCOPE_AGENT);
      out[0] = (float)(S / M);
    }
  }
}

extern "C" void kernel_launch(void* const* d_in, const int* in_sizes, int n_in,
                              void* d_out, int out_size, void* d_ws, size_t ws_size,
                              hipStream_t stream) {
  const float* emb = (const float*)d_in[0];
  const int* labels = (const int*)d_in[1];
  float* out = (float*)d_out;

  // ws: Ebf[4MB] | sq[32KB] | numpart[2MB] | denpart[2MB] | Ssum | counter
  char* w = (char*)d_ws;
  __hip_bfloat16* Ebf = (__hip_bfloat16*)w;
  float* sq = (float*)(w + (size_t)N * E * 2);
  float* numpart = sq + N;
  float* denpart = numpart + (size_t)MT * N;
  double* Ssum = (double*)(denpart + (size_t)MT * N);
  int* counter = (int*)(Ssum + 1);

  prep_kernel<<<N / 16, 256, 0, stream>>>(emb, Ebf, sq, Ssum, counter);
  gram_kernel<<<NTILES, 256, 0, stream>>>(Ebf, sq, labels, numpart, denpart);
  fin_kernel<<<FIN_BLOCKS, 256, 0, stream>>>(numpart, denpart, labels, Ssum,
                                             counter, out);
}

// Round 6
// 127.860 us; speedup vs baseline: 2.0015x; 1.0047x over previous
//
#include <hip/hip_runtime.h>
#include <hip/hip_bf16.h>
#include <stdint.h>

#define N 8192
#define E 256
#define NUM_CLASSES 100
#define MARGIN 0.1f
#define EPS 1e-4f

#define BT 128           // tile dim (M and N of a Gram tile)
#define MT (N / BT)      // 64 tile-rows -> 2080 upper-tri tiles
#define NTILES (MT * (MT + 1) / 2)
#define EB 256           // fp8 row = 256 B
#define FIN_BLOCKS (N / 256)  // 32

typedef __attribute__((ext_vector_type(4))) float floatx4;  // MFMA C/D

typedef const __attribute__((address_space(1))) void* gptr_t;
typedef __attribute__((address_space(3))) void* sptr_t;

// 16-lane butterfly sum on the VALU via DPP (no LDS-pipe usage).
__device__ __forceinline__ float dpp_sum16(float v) {
  v += __int_as_float(__builtin_amdgcn_update_dpp(0, __float_as_int(v), 0xB1, 0xF, 0xF, true));
  v += __int_as_float(__builtin_amdgcn_update_dpp(0, __float_as_int(v), 0x4E, 0xF, 0xF, true));
  v += __int_as_float(__builtin_amdgcn_update_dpp(0, __float_as_int(v), 0x141, 0xF, 0xF, true));
  v += __int_as_float(__builtin_amdgcn_update_dpp(0, __float_as_int(v), 0x140, 0xF, 0xF, true));
  return v;
}

// --- Kernel 1: fp8 e4m3 cast + fp32 row norms; block 0 zeroes Ssum/counter ---
__global__ __launch_bounds__(256) void prep_kernel(
    const float* __restrict__ emb, unsigned char* __restrict__ Efp8,
    float* __restrict__ sq, double* __restrict__ Ssum, int* __restrict__ counter)
{
  const int lane = threadIdx.x & 63;
  const int wave = threadIdx.x >> 6;
  if (blockIdx.x == 0 && threadIdx.x == 0) {
    *Ssum = 0.0;
    *counter = 0;
  }
  #pragma unroll
  for (int i = 0; i < 4; ++i) {
    const int row = blockIdx.x * 16 + i * 4 + wave;
    const float4 x = *(const float4*)(emb + (size_t)row * E + lane * 4);
    // pack 4 floats -> 4 OCP e4m3 bytes (gfx950 fp8 is OCP, not fnuz)
    int pk = __builtin_amdgcn_cvt_pk_fp8_f32(x.x, x.y, 0, false);
    pk = __builtin_amdgcn_cvt_pk_fp8_f32(x.z, x.w, pk, true);
    ((unsigned int*)(Efp8 + (size_t)row * EB))[lane] = (unsigned int)pk;
    float s = x.x * x.x + x.y * x.y + x.z * x.z + x.w * x.w;
    #pragma unroll
    for (int off = 32; off > 0; off >>= 1) s += __shfl_down(s, off, 64);
    if (lane == 0) sq[row] = s;
  }
}

// --- Kernel 2: 128x128-tile fp8 MFMA Gram, triangular grid, atomic-free ------
// 2 K-stages of 128 (vs 4 of 64 in bf16) -> half the vmcnt(0)+barrier drains.
// LDS 16 KB/tile/stage, 34 KB total -> 3-4 blocks/CU. Frags are b64 (2 VGPRs).
// XOR swizzle at 16-B granularity: LDS chunk (r, cc) holds global k-chunk
// cc^(r&7); frag reads then hit the 4-access/bank minimum for b64 (no extra
// conflicts). Diagonal elements forced to d2=EPS (exact ref match; kills the
// fp8-sensitive 2sq-2dot cancellation).
__global__ __launch_bounds__(256, 2) void gram_kernel(
    const unsigned char* __restrict__ Efp8, const float* __restrict__ sq,
    const int* __restrict__ labels, float* __restrict__ numpart,
    float* __restrict__ denpart)
{
  // decode linear tile id -> (by, bx), bx >= by
  const int t = blockIdx.x;
  int by = (int)((2.0 * MT + 1.0 - __builtin_sqrt((2.0 * MT + 1.0) * (2.0 * MT + 1.0) - 8.0 * t)) * 0.5);
  while (by * MT - by * (by - 1) / 2 > t) --by;
  while ((by + 1) * MT - (by + 1) * by / 2 <= t) ++by;
  const int bx = by + (t - (by * MT - by * (by - 1) / 2));
  const bool diag = (bx == by);

  __shared__ alignas(16) unsigned char As[BT * 128];  // 16 KB (one K=128 slab)
  __shared__ alignas(16) unsigned char Bs[BT * 128];  // 16 KB
  __shared__ float redAcc[512];  // rnum|rden|cnum|cden (2 KB)
  float* const rnum = redAcc;
  float* const rden = redAcc + 128;
  float* const cnum = redAcc + 256;
  float* const cden = redAcc + 384;

  const int tid = threadIdx.x;
  const int lane = tid & 63;
  const int wave = tid >> 6;
  const int waveM = wave >> 1;
  const int waveN = wave & 1;
  const int quad = lane >> 4;
  const int l16 = lane & 15;

  const int rowBase = by * BT;
  const int colBase = bx * BT;

  redAcc[tid] = 0.f;
  redAcc[tid + 256] = 0.f;

  floatx4 acc[4][4];
  #pragma unroll
  for (int i = 0; i < 4; ++i)
    #pragma unroll
    for (int j = 0; j < 4; ++j)
      acc[i][j] = (floatx4){0.f, 0.f, 0.f, 0.f};

  const char* gbase = (const char*)Efp8;

  for (int s = 0; s < 2; ++s) {  // two K=128 stages
    // Stage 16 KB per tile = 4 rounds x 256 threads x 16 B, swizzled source:
    // LDS chunk c=(r, cc) <- global k-chunk cc^(r&7) of row r.
    #pragma unroll
    for (int it = 0; it < 4; ++it) {
      const int c = it * 256 + tid;       // chunk 0..1023
      const int r = c >> 3;               // tile row (128-B k-rows, 8 chunks)
      const int kq = (c & 7) ^ (r & 7);
      const int srcoff = s * 128 + kq * 16;
      const int dstoff = c * 16;
      const char* gA = gbase + (size_t)(rowBase + r) * EB + srcoff;
      __builtin_amdgcn_global_load_lds((gptr_t)gA, (sptr_t)((char*)As + dstoff), 16, 0, 0);
      if (!diag) {
        const char* gB = gbase + (size_t)(colBase + r) * EB + srcoff;
        __builtin_amdgcn_global_load_lds((gptr_t)gB, (sptr_t)((char*)Bs + dstoff), 16, 0, 0);
      }
    }
    __syncthreads();

    const unsigned char* Bsrc = diag ? As : Bs;
    #pragma unroll
    for (int ks = 0; ks < 4; ++ks) {  // four K=32 MFMA steps per stage
      // lane reads k-bytes [ks*32 + quad*8, +8): chunk cc0=2ks+(quad>>1),
      // half (quad&1)*8, swizzled by row.
      const int cc0 = 2 * ks + (quad >> 1);
      const int hf = (quad & 1) * 8;
      long af[4], bf[4];
      #pragma unroll
      for (int mi = 0; mi < 4; ++mi) {
        const int r = waveM * 64 + mi * 16 + l16;
        af[mi] = *(const long*)((const char*)As + r * 128 + ((cc0 ^ (r & 7)) << 4) + hf);
      }
      #pragma unroll
      for (int ni = 0; ni < 4; ++ni) {
        const int r = waveN * 64 + ni * 16 + l16;
        bf[ni] = *(const long*)((const char*)Bsrc + r * 128 + ((cc0 ^ (r & 7)) << 4) + hf);
      }
      #pragma unroll
      for (int mi = 0; mi < 4; ++mi)
        #pragma unroll
        for (int ni = 0; ni < 4; ++ni)
          acc[mi][ni] = __builtin_amdgcn_mfma_f32_16x16x32_fp8_fp8(
              af[mi], bf[ni], acc[mi][ni], 0, 0, 0);
    }
    __syncthreads();
  }

  // Epilogue. C/D layout: col = lane&15, row = quad*4 + reg (shape-determined).
  float sqc[4];
  int lc[4], cg[4];
  #pragma unroll
  for (int ni = 0; ni < 4; ++ni) {
    const int col = colBase + waveN * 64 + ni * 16 + l16;
    sqc[ni] = sq[col];
    lc[ni] = labels[col];
    cg[ni] = col;
  }

  float ncp[4] = {0.f, 0.f, 0.f, 0.f};
  float dcp[4] = {0.f, 0.f, 0.f, 0.f};

  #pragma unroll
  for (int mi = 0; mi < 4; ++mi) {
    const int rbase = rowBase + waveM * 64 + mi * 16 + quad * 4;
    const float4 sqr4 = *(const float4*)(sq + rbase);
    const int4 lr4 = *(const int4*)(labels + rbase);
    const float sqr[4] = {sqr4.x, sqr4.y, sqr4.z, sqr4.w};
    const int lr[4] = {lr4.x, lr4.y, lr4.z, lr4.w};
    float npv[4], dpv[4];
    #pragma unroll
    for (int r = 0; r < 4; ++r) {
      float np = 0.f, dp = 0.f;
      #pragma unroll
      for (int ni = 0; ni < 4; ++ni) {
        float d2 = fmaxf(fmaf(-2.f, acc[mi][ni][r], sqr[r] + sqc[ni]), EPS);
        if (diag && (rbase + r == cg[ni])) d2 = EPS;  // exact diagonal
        float d = __builtin_amdgcn_sqrtf(d2);
        float rc = __builtin_amdgcn_rcpf(d + MARGIN);
        const bool same = (lr[r] == lc[ni]);
        const float dsel = same ? d : 0.f;
        const float rsel = same ? 0.f : rc;
        np += dsel; dp += rsel;
        ncp[ni] += dsel; dcp[ni] += rsel;
      }
      npv[r] = dpp_sum16(np);
      dpv[r] = dpp_sum16(dp);
    }
    const float seln = (l16 & 2) ? ((l16 & 1) ? npv[3] : npv[2])
                                 : ((l16 & 1) ? npv[1] : npv[0]);
    const float seld = (l16 & 2) ? ((l16 & 1) ? dpv[3] : dpv[2])
                                 : ((l16 & 1) ? dpv[1] : dpv[0]);
    if ((l16 >> 2) == quad) {
      atomicAdd(&rnum[waveM * 64 + mi * 16 + l16], seln);
      atomicAdd(&rden[waveM * 64 + mi * 16 + l16], seld);
    }
  }

  if (!diag) {
    #pragma unroll
    for (int ni = 0; ni < 4; ++ni) {
      atomicAdd(&cnum[waveN * 64 + ni * 16 + l16], ncp[ni]);
      atomicAdd(&cden[waveN * 64 + ni * 16 + l16], dcp[ni]);
    }
  }
  __syncthreads();

  // unique-writer global stores: tile(by,bx): rows -> part[bx], cols -> part[by]
  if (tid < 128) {
    numpart[(size_t)bx * N + rowBase + tid] = rnum[tid];
    denpart[(size_t)bx * N + rowBase + tid] = rden[tid];
  } else if (!diag) {
    const int i = tid - 128;
    numpart[(size_t)by * N + colBase + i] = cnum[i];
    denpart[(size_t)by * N + colBase + i] = cden[i];
  }
}

// --- Kernel 3: fold partials, S-reduce, last block does m_sum + divide -------
__global__ __launch_bounds__(256) void fin_kernel(
    const float* __restrict__ numpart, const float* __restrict__ denpart,
    const int* __restrict__ labels, double* __restrict__ Ssum,
    int* __restrict__ counter, float* __restrict__ out)
{
  __shared__ double sh[4];
  __shared__ int lastflag;
  __shared__ int hist[NUM_CLASSES];
  __shared__ double shm[4];

  const int tid = threadIdx.x;
  const int lane = tid & 63;
  const int wave = tid >> 6;
  const int a = blockIdx.x * 256 + tid;

  float np = 0.f, dp = 0.f;
  #pragma unroll 4
  for (int k = 0; k < MT; ++k) {
    np += numpart[(size_t)k * N + a];
    dp += denpart[(size_t)k * N + a];
  }
  double s = (double)np * (double)dp;
  #pragma unroll
  for (int off = 32; off > 0; off >>= 1) s += __shfl_down(s, off, 64);
  if (lane == 0) sh[wave] = s;
  __syncthreads();
  if (tid == 0) {
    unsafeAtomicAdd(Ssum, sh[0] + sh[1] + sh[2] + sh[3]);
    __threadfence();
    const int prev = __hip_atomic_fetch_add(counter, 1, __ATOMIC_ACQ_REL,
                                            __HIP_MEMORY_SCOPE_AGENT);
    lastflag = (prev == FIN_BLOCKS - 1) ? 1 : 0;
  }
  __syncthreads();

  if (lastflag) {
    if (tid < NUM_CLASSES) hist[tid] = 0;
    __syncthreads();
    for (int i = tid; i < N; i += 256) atomicAdd(&hist[labels[i]], 1);
    __syncthreads();
    double m = 0.0;
    if (tid < NUM_CLASSES) {
      const double cc = (double)hist[tid];
      m = cc * cc * (double)(N - cc);
    }
    #pragma unroll
    for (int off = 32; off > 0; off >>= 1) m += __shfl_down(m, off, 64);
    if (lane == 0) shm[wave] = m;
    __syncthreads();
    if (tid == 0) {
      const double M = shm[0] + shm[1] + shm[2] + shm[3];
      const double S = __hip_atomic_load(Ssum, __ATOMIC_RELAXED,
                                         __HIP_MEMORY_SCOPE_AGENT);
      out[0] = (float)(S / M);
    }
  }
}

extern "C" void kernel_launch(void* const* d_in, const int* in_sizes, int n_in,
                              void* d_out, int out_size, void* d_ws, size_t ws_size,
                              hipStream_t stream) {
  const float* emb = (const float*)d_in[0];
  const int* labels = (const int*)d_in[1];
  float* out = (float*)d_out;

  // ws: Efp8[2MB] | sq[32KB] | numpart[2MB] | denpart[2MB] | Ssum | counter
  char* w = (char*)d_ws;
  unsigned char* Efp8 = (unsigned char*)w;
  float* sq = (float*)(w + (size_t)N * EB);
  float* numpart = sq + N;
  float* denpart = numpart + (size_t)MT * N;
  double* Ssum = (double*)(denpart + (size_t)MT * N);
  int* counter = (int*)(Ssum + 1);

  prep_kernel<<<N / 16, 256, 0, stream>>>(emb, Efp8, sq, Ssum, counter);
  gram_kernel<<<NTILES, 256, 0, stream>>>(Efp8, sq, labels, numpart, denpart);
  fin_kernel<<<FIN_BLOCKS, 256, 0, stream>>>(numpart, denpart, labels, Ssum,
                                             counter, out);
}